// Round 7
// baseline (148.048 us; speedup 1.0000x reference)
//
#include <hip/hip_runtime.h>
#include <hip/hip_fp16.h>
#include <math.h>

// Problem constants: B=2, K=128, L=4096, DK=DL=128, HID=128
constexpr int BB = 2;
constexpr int KK = 128;
constexpr int LL = 4096;
constexpr int DD = 128;
constexpr int HH = 128;
constexpr int NBLK = 256;      // 1 block per CU

__device__ __forceinline__ float4 ld4(const float* p) {
    return *reinterpret_cast<const float4*>(p);
}

// packed fp16 max — emits v_pk_max_f16
__device__ __forceinline__ __half2 hmax2(__half2 a, __half2 b) {
    unsigned ua = __builtin_bit_cast(unsigned, a);
    unsigned ub = __builtin_bit_cast(unsigned, b);
    unsigned ud;
    asm("v_pk_max_f16 %0, %1, %2" : "=v"(ud) : "v"(ua), "v"(ub));
    return __builtin_bit_cast(__half2, ud);
}

// duplicate fp16(x) into both halves of a dword
__device__ __forceinline__ uint32_t duph(float x) {
    __half h = __float2half(x);
    unsigned short us = __builtin_bit_cast(unsigned short, h);
    return (uint32_t)us * 0x10001u;
}

// ---------------------------------------------------------------------------
// Single fused kernel. 256 blocks x 256 threads (1 block/CU).
// P1: GEMM tiles (t = bid, bid+256 over 264 tiles of 32 virtual rows)
//     A-rows -> u_dup (fp16 dup'd), B-rows -> vT[b][h][l] fp16; w2 -> w2_dup.
// Hand-rolled device barrier (bar[0]=count, bar[16]=flag; zeroed by memset node)
// P2: block = one (b,k) row: scores via pk-fp16 (u,w2 scalar-uniform loads;
//     v as uint4), in-register softmax, coalesced float4 stores.
// ---------------------------------------------------------------------------
__global__ __launch_bounds__(256) void fused(
    const float* __restrict__ inA, const float* __restrict__ inB,
    const float* __restrict__ W1, const float* __restrict__ b1,
    const float* __restrict__ w2,
    uint32_t* __restrict__ u_dup, uint32_t* __restrict__ w2_dup,
    __half* __restrict__ vT, int* __restrict__ bar,
    float* __restrict__ out)
{
    __shared__ __align__(16) float sIn[32 * 128];   // 16 KiB
    __shared__ float sT[128 * 33];                  // 16.9 KiB

    const int tid = threadIdx.x;
    const int bid = blockIdx.x;

    // ============================ P1: GEMM ================================
    for (int t = bid; t < 264; t += NBLK) {
        const int row0 = t * 32;
        const bool isA = (row0 < BB * KK);
        const float* src = isA ? (inA + (size_t)row0 * DD)
                               : (inB + (size_t)(row0 - BB * KK) * DD);
        const float* w   = W1 + (isA ? 0 : DD * HH);

        #pragma unroll
        for (int j = 0; j < 4; ++j) {
            const int idx = tid + 256 * j;
            reinterpret_cast<float4*>(sIn)[idx] =
                reinterpret_cast<const float4*>(src)[idx];
        }
        __syncthreads();

        const int tx = tid & 31;
        const int ty = tid >> 5;

        float accx[4], accy[4], accz[4], accw[4];
        #pragma unroll
        for (int r = 0; r < 4; ++r) { accx[r] = accy[r] = accz[r] = accw[r] = 0.f; }

        for (int d0 = 0; d0 < DD; d0 += 4) {
            float4 w4[4];
            #pragma unroll
            for (int dd = 0; dd < 4; ++dd)
                w4[dd] = ld4(&w[(size_t)(d0 + dd) * HH + tx * 4]);
            float a[4][4];
            #pragma unroll
            for (int r = 0; r < 4; ++r) {
                float4 a4 = ld4(&sIn[(ty * 4 + r) * 128 + d0]);
                a[r][0] = a4.x; a[r][1] = a4.y; a[r][2] = a4.z; a[r][3] = a4.w;
            }
            #pragma unroll
            for (int dd = 0; dd < 4; ++dd) {
                const float4 wv = w4[dd];
                #pragma unroll
                for (int r = 0; r < 4; ++r) {
                    const float av = a[r][dd];
                    accx[r] = fmaf(av, wv.x, accx[r]);
                    accy[r] = fmaf(av, wv.y, accy[r]);
                    accz[r] = fmaf(av, wv.z, accz[r]);
                    accw[r] = fmaf(av, wv.w, accw[r]);
                }
            }
        }

        if (isA) {
            const float4 bb = ld4(&b1[tx * 4]);
            #pragma unroll
            for (int r = 0; r < 4; ++r) {
                uint4 o;
                o.x = duph(accx[r] + bb.x);
                o.y = duph(accy[r] + bb.y);
                o.z = duph(accz[r] + bb.z);
                o.w = duph(accw[r] + bb.w);
                *reinterpret_cast<uint4*>(
                    &u_dup[(size_t)(row0 + ty * 4 + r) * HH + tx * 4]) = o;
            }
            if (t == 0 && tid < HH) w2_dup[tid] = duph(w2[tid]);
            __syncthreads();   // keep LDS lifetime consistent across loop
        } else {
            #pragma unroll
            for (int r = 0; r < 4; ++r) {
                const int l = ty * 4 + r;
                sT[(tx * 4 + 0) * 33 + l] = accx[r];
                sT[(tx * 4 + 1) * 33 + l] = accy[r];
                sT[(tx * 4 + 2) * 33 + l] = accz[r];
                sT[(tx * 4 + 3) * 33 + l] = accw[r];
            }
            __syncthreads();
            const int h    = tid >> 1;
            const int half = tid & 1;
            const int rowB = row0 - BB * KK;
            const int bsel = rowB >> 12;
            const int l0   = (rowB & 4095) + half * 16;
            uint32_t o[8];
            #pragma unroll
            for (int i = 0; i < 8; ++i) {
                const float lo = sT[h * 33 + half * 16 + 2 * i];
                const float hi = sT[h * 33 + half * 16 + 2 * i + 1];
                o[i] = __builtin_bit_cast(uint32_t, __floats2half2_rn(lo, hi));
            }
            uint32_t* dst = reinterpret_cast<uint32_t*>(vT) +
                            ((size_t)(bsel * HH + h) * LL + l0) / 2;
            uint4 s0; s0.x = o[0]; s0.y = o[1]; s0.z = o[2]; s0.w = o[3];
            uint4 s1; s1.x = o[4]; s1.y = o[5]; s1.z = o[6]; s1.w = o[7];
            *reinterpret_cast<uint4*>(dst)     = s0;
            *reinterpret_cast<uint4*>(dst + 4) = s1;
        }
        __syncthreads();
    }

    // ====================== device-wide barrier ===========================
    __syncthreads();
    if (tid == 0) {
        __threadfence();   // make this block's vT/u_dup writes device-visible
        int old = __hip_atomic_fetch_add(&bar[0], 1, __ATOMIC_ACQ_REL,
                                         __HIP_MEMORY_SCOPE_AGENT);
        if (old == NBLK - 1) {
            __hip_atomic_store(&bar[16], 1, __ATOMIC_RELEASE,
                               __HIP_MEMORY_SCOPE_AGENT);
        } else {
            while (__hip_atomic_load(&bar[16], __ATOMIC_ACQUIRE,
                                     __HIP_MEMORY_SCOPE_AGENT) == 0)
                __builtin_amdgcn_s_sleep(2);
        }
    }
    __syncthreads();
    __threadfence();

    // ==================== P2: scores + softmax ============================
    {
        const int row = bid;            // 0..255 = b*KK + k
        const int b   = row >> 7;
        const uint32_t* vpb = reinterpret_cast<const uint32_t*>(vT)
                              + (size_t)b * HH * (LL / 2);
        const uint32_t* up  = u_dup + (size_t)row * HH;   // uniform -> s_load
        const uint32_t* v0p = vpb + 4 * tid;              // l-pairs 4t..4t+3
        const uint32_t* v1p = vpb + 1024 + 4 * tid;       // l-pairs 1024+4t..

        const __half2 hz = __float2half2_rn(0.f);
        float2 facc[8];
        #pragma unroll
        for (int i = 0; i < 8; ++i) { facc[i].x = 0.f; facc[i].y = 0.f; }

        for (int g = 0; g < 8; ++g) {          // 16 h per group
            __half2 a0[4], a1[4];
            #pragma unroll
            for (int q = 0; q < 4; ++q) { a0[q] = hz; a1[q] = hz; }

            #pragma unroll
            for (int j = 0; j < 16; ++j) {
                const int h = g * 16 + j;
                const __half2 uu = __builtin_bit_cast(__half2, up[h]);
                const __half2 ww = __builtin_bit_cast(__half2, w2_dup[h]);
                const uint4 v0 = *reinterpret_cast<const uint4*>(
                                     v0p + (size_t)h * (LL / 2));
                const uint4 v1 = *reinterpret_cast<const uint4*>(
                                     v1p + (size_t)h * (LL / 2));
                const uint32_t* q0 = reinterpret_cast<const uint32_t*>(&v0);
                const uint32_t* q1 = reinterpret_cast<const uint32_t*>(&v1);
                #pragma unroll
                for (int q = 0; q < 4; ++q) {
                    __half2 t0 = __hadd2(__builtin_bit_cast(__half2, q0[q]), uu);
                    __half2 t1 = __hadd2(__builtin_bit_cast(__half2, q1[q]), uu);
                    a0[q] = __hfma2(hmax2(t0, hz), ww, a0[q]);
                    a1[q] = __hfma2(hmax2(t1, hz), ww, a1[q]);
                }
            }
            #pragma unroll
            for (int q = 0; q < 4; ++q) {
                const float2 f0 = __half22float2(a0[q]);
                const float2 f1 = __half22float2(a1[q]);
                facc[q].x     += f0.x; facc[q].y     += f0.y;
                facc[4 + q].x += f1.x; facc[4 + q].y += f1.y;
            }
        }

        // ---- softmax over the row (16 scores/thread, 4 waves) ----
        float* red = sT;    // reuse LDS
        float m = facc[0].x;
        #pragma unroll
        for (int i = 0; i < 8; ++i)
            m = fmaxf(m, fmaxf(facc[i].x, facc[i].y));
        #pragma unroll
        for (int off = 32; off > 0; off >>= 1)
            m = fmaxf(m, __shfl_xor(m, off, 64));
        const int lane = tid & 63, wv = tid >> 6;
        if (lane == 0) red[wv] = m;
        __syncthreads();
        m = fmaxf(fmaxf(red[0], red[1]), fmaxf(red[2], red[3]));
        __syncthreads();

        float s = 0.f;
        #pragma unroll
        for (int i = 0; i < 8; ++i) {
            facc[i].x = expf(facc[i].x - m); s += facc[i].x;
            facc[i].y = expf(facc[i].y - m); s += facc[i].y;
        }
        #pragma unroll
        for (int off = 32; off > 0; off >>= 1)
            s += __shfl_xor(s, off, 64);
        if (lane == 0) red[8 + wv] = s;
        __syncthreads();
        s = (red[8] + red[9]) + (red[10] + red[11]);

        const float inv = 1.0f / s;
        float* po = out + (size_t)row * LL;
        float4 o;
        o.x = facc[0].x * inv; o.y = facc[0].y * inv;
        o.z = facc[1].x * inv; o.w = facc[1].y * inv;
        *reinterpret_cast<float4*>(&po[8 * tid]) = o;
        o.x = facc[2].x * inv; o.y = facc[2].y * inv;
        o.z = facc[3].x * inv; o.w = facc[3].y * inv;
        *reinterpret_cast<float4*>(&po[8 * tid + 4]) = o;
        o.x = facc[4].x * inv; o.y = facc[4].y * inv;
        o.z = facc[5].x * inv; o.w = facc[5].y * inv;
        *reinterpret_cast<float4*>(&po[2048 + 8 * tid]) = o;
        o.x = facc[6].x * inv; o.y = facc[6].y * inv;
        o.z = facc[7].x * inv; o.w = facc[7].y * inv;
        *reinterpret_cast<float4*>(&po[2048 + 8 * tid + 4]) = o;
    }
}

// ---------------------------------------------------------------------------
extern "C" void kernel_launch(void* const* d_in, const int* in_sizes, int n_in,
                              void* d_out, int out_size, void* d_ws, size_t ws_size,
                              hipStream_t stream)
{
    const float* inA = (const float*)d_in[0];
    const float* inB = (const float*)d_in[1];
    const float* W1  = (const float*)d_in[2];
    const float* b1  = (const float*)d_in[3];
    const float* w2  = (const float*)d_in[4];
    float* out = (float*)d_out;

    uint32_t* u_dup  = (uint32_t*)d_ws;                            // 128 KiB
    uint32_t* w2_dup = (uint32_t*)((char*)d_ws + 128 * 1024);      // 512 B
    __half*   vT     = (__half*)((char*)d_ws + 128 * 1024 + 512);  // 2 MiB
    int*      bar    = (int*)((char*)d_ws + 8 * 1024 * 1024);      // barrier

    hipMemsetAsync(bar, 0, 128, stream);   // capturable memset node
    hipLaunchKernelGGL(fused, dim3(NBLK), dim3(256), 0, stream,
                       inA, inB, W1, b1, w2, u_dup, w2_dup, vT, bar, out);
}

// Round 8
// 33.945 us; speedup vs baseline: 4.3614x; 4.3614x over previous
//
#include <hip/hip_runtime.h>
#include <hip/hip_fp16.h>
#include <math.h>

// Problem constants: B=2, K=128, L=4096, DK=DL=128, HID=128
constexpr int BB = 2;
constexpr int KK = 128;
constexpr int LL = 4096;
constexpr int DD = 128;
constexpr int HH = 128;

__device__ __forceinline__ float4 ld4(const float* p) {
    return *reinterpret_cast<const float4*>(p);
}

// packed fp16 max — emits v_pk_max_f16
__device__ __forceinline__ __half2 hmax2(__half2 a, __half2 b) {
    unsigned ua = __builtin_bit_cast(unsigned, a);
    unsigned ub = __builtin_bit_cast(unsigned, b);
    unsigned ud;
    asm("v_pk_max_f16 %0, %1, %2" : "=v"(ud) : "v"(ua), "v"(ub));
    return __builtin_bit_cast(__half2, ud);
}

// duplicate fp16(x) into both halves of a dword
__device__ __forceinline__ uint32_t duph(float x) {
    __half h = __float2half(x);
    unsigned short us = __builtin_bit_cast(unsigned short, h);
    return (uint32_t)us * 0x10001u;
}

// ---------------------------------------------------------------------------
// K1: 528 blocks x 256 threads, 16 rows each. 2 blocks/CU.
//  j in [0,512): B-tile. XCD-swizzled: chunk C = j&15 (512 l of one b),
//    sub s = j>>4 (0..31). Tile rows: rowB0 = (C*32+s)*16. Since j%8 == C%8,
//    all tiles of chunk C run on XCD C%8 -> vT chunk stays in that L2.
//  j in [512,528): A-tile ta = j-512, rows ta*16 of u. j==512 packs w2_dup.
// ---------------------------------------------------------------------------
__global__ __launch_bounds__(256) void k1_gemm(
    const float* __restrict__ inA, const float* __restrict__ inB,
    const float* __restrict__ W1, const float* __restrict__ b1,
    const float* __restrict__ w2,
    uint32_t* __restrict__ u_dup, uint32_t* __restrict__ w2_dup,
    __half* __restrict__ vT)
{
    __shared__ __align__(16) float sIn[16 * 128];   // 8 KiB input tile
    __shared__ float sT[128 * 17];                  // 8.5 KiB transpose tile

    const int j = blockIdx.x;
    const bool isA = (j >= 512);
    int row0;                       // first row within its space
    if (isA) {
        row0 = (j - 512) * 16;      // u rows
    } else {
        const int C = j & 15, s = j >> 4;
        row0 = (C * 32 + s) * 16;   // B virtual rows 0..8191
    }
    const float* src = isA ? (inA + (size_t)row0 * DD)
                           : (inB + (size_t)row0 * DD);
    const float* w   = W1 + (isA ? 0 : DD * HH);

    const int tid = threadIdx.x;

    // stage 16x128 input rows (coalesced float4)
    #pragma unroll
    for (int q = 0; q < 2; ++q) {
        const int idx = tid + 256 * q;
        reinterpret_cast<float4*>(sIn)[idx] =
            reinterpret_cast<const float4*>(src)[idx];
    }
    __syncthreads();

    const int tx = tid & 31;   // cols tx*4..tx*4+3 (h)
    const int ty = tid >> 5;   // 0..7 -> rows ty*2, ty*2+1

    float acc[2][4];
    #pragma unroll
    for (int r = 0; r < 2; ++r)
        #pragma unroll
        for (int c = 0; c < 4; ++c) acc[r][c] = 0.f;

    for (int d0 = 0; d0 < DD; d0 += 4) {
        float4 w4[4];
        #pragma unroll
        for (int dd = 0; dd < 4; ++dd)
            w4[dd] = ld4(&w[(size_t)(d0 + dd) * HH + tx * 4]);
        float a[2][4];
        #pragma unroll
        for (int r = 0; r < 2; ++r) {
            float4 a4 = ld4(&sIn[(ty * 2 + r) * 128 + d0]);
            a[r][0] = a4.x; a[r][1] = a4.y; a[r][2] = a4.z; a[r][3] = a4.w;
        }
        #pragma unroll
        for (int dd = 0; dd < 4; ++dd) {
            #pragma unroll
            for (int r = 0; r < 2; ++r) {
                const float av = a[r][dd];
                acc[r][0] = fmaf(av, w4[dd].x, acc[r][0]);
                acc[r][1] = fmaf(av, w4[dd].y, acc[r][1]);
                acc[r][2] = fmaf(av, w4[dd].z, acc[r][2]);
                acc[r][3] = fmaf(av, w4[dd].w, acc[r][3]);
            }
        }
    }

    if (isA) {
        const float4 bb = ld4(&b1[tx * 4]);
        #pragma unroll
        for (int r = 0; r < 2; ++r) {
            uint4 o;
            o.x = duph(acc[r][0] + bb.x);
            o.y = duph(acc[r][1] + bb.y);
            o.z = duph(acc[r][2] + bb.z);
            o.w = duph(acc[r][3] + bb.w);
            *reinterpret_cast<uint4*>(
                &u_dup[(size_t)(row0 + ty * 2 + r) * HH + tx * 4]) = o;
        }
        if (j == 512 && tid < HH) w2_dup[tid] = duph(w2[tid]);
    } else {
        // transpose through padded LDS: sT[h][l], stride 17
        #pragma unroll
        for (int r = 0; r < 2; ++r) {
            const int l = ty * 2 + r;
            sT[(tx * 4 + 0) * 17 + l] = acc[r][0];
            sT[(tx * 4 + 1) * 17 + l] = acc[r][1];
            sT[(tx * 4 + 2) * 17 + l] = acc[r][2];
            sT[(tx * 4 + 3) * 17 + l] = acc[r][3];
        }
        __syncthreads();
        // store-out: thread = (h, half); 8 l-values -> 4 half2 dwords (uint4)
        const int h    = tid >> 1;
        const int half = tid & 1;
        const int bsel = row0 >> 12;
        const int l0g  = (row0 & 4095) + half * 8;
        uint4 o;
        uint32_t* op = reinterpret_cast<uint32_t*>(&o);
        #pragma unroll
        for (int i = 0; i < 4; ++i) {
            const float lo = sT[h * 17 + half * 8 + 2 * i];
            const float hi = sT[h * 17 + half * 8 + 2 * i + 1];
            op[i] = __builtin_bit_cast(uint32_t, __floats2half2_rn(lo, hi));
        }
        uint32_t* dst = reinterpret_cast<uint32_t*>(vT) +
                        (size_t)(bsel * HH + h) * (LL / 2) + l0g / 2;
        *reinterpret_cast<uint4*>(dst) = o;
    }
}

// ---------------------------------------------------------------------------
// K2: scores. 512 blocks x 256 threads (2 blocks/CU). Block m = cb + 8*q,
// q = kt + 32*b -> block reads v-chunk cb on XCD cb%8 (where k1 wrote it).
// Thread: one l-pair (half2) x 4 k-rows. u(4 rows)+w2 staged in LDS, v as
// batched dword loads. fp16 acc flushed to f32 every 16 h (same as R4-R7).
// ---------------------------------------------------------------------------
__global__ __launch_bounds__(256) void k2_score(
    const uint32_t* __restrict__ u_dup, const uint32_t* __restrict__ w2_dup,
    const __half* __restrict__ vT, float* __restrict__ out)
{
    __shared__ __align__(16) uint32_t sU[4 * HH];   // 2 KiB
    __shared__ __align__(16) uint32_t sW[HH];       // 512 B

    int m = blockIdx.x;
    const int cb = m & 7;   m >>= 3;
    const int kt = m & 31;  m >>= 5;
    const int b  = m;
    const int tid = threadIdx.x;

    if (tid < 128)
        reinterpret_cast<uint4*>(sU)[tid] =
            reinterpret_cast<const uint4*>(u_dup + (size_t)(b * KK + kt * 4) * HH)[tid];
    else if (tid < 160)
        reinterpret_cast<uint4*>(sW)[tid - 128] =
            reinterpret_cast<const uint4*>(w2_dup)[tid - 128];
    __syncthreads();

    const int p = cb * 256 + tid;   // l-pair index within b; l = 2p
    const uint32_t* vp = reinterpret_cast<const uint32_t*>(vT)
                         + (size_t)b * HH * (LL / 2) + p;

    const __half2 hz = __float2half2_rn(0.f);
    float2 facc[4];
    #pragma unroll
    for (int k = 0; k < 4; ++k) { facc[k].x = 0.f; facc[k].y = 0.f; }

    for (int g = 0; g < 8; ++g) {          // 16 h per group
        const int h0 = g * 16;
        // batched independent v-loads (MLP)
        uint32_t v[16];
        #pragma unroll
        for (int jj = 0; jj < 16; ++jj)
            v[jj] = vp[(size_t)(h0 + jj) * (LL / 2)];

        __half2 acc[4];
        #pragma unroll
        for (int k = 0; k < 4; ++k) acc[k] = hz;

        #pragma unroll
        for (int k = 0; k < 4; ++k) {
            #pragma unroll
            for (int q = 0; q < 4; ++q) {
                const uint4 uc = *reinterpret_cast<const uint4*>(&sU[k * HH + h0 + q * 4]);
                const uint4 wc = *reinterpret_cast<const uint4*>(&sW[h0 + q * 4]);
                const uint32_t* uq = reinterpret_cast<const uint32_t*>(&uc);
                const uint32_t* wq = reinterpret_cast<const uint32_t*>(&wc);
                #pragma unroll
                for (int jj = 0; jj < 4; ++jj) {
                    const __half2 uu = __builtin_bit_cast(__half2, uq[jj]);
                    const __half2 ww = __builtin_bit_cast(__half2, wq[jj]);
                    __half2 t = __hadd2(__builtin_bit_cast(__half2, v[q * 4 + jj]), uu);
                    acc[k] = __hfma2(hmax2(t, hz), ww, acc[k]);
                }
            }
        }
        #pragma unroll
        for (int k = 0; k < 4; ++k) {
            const float2 f = __half22float2(acc[k]);
            facc[k].x += f.x; facc[k].y += f.y;
        }
    }

    #pragma unroll
    for (int k = 0; k < 4; ++k)
        *reinterpret_cast<float2*>(
            &out[(size_t)(b * KK + kt * 4 + k) * LL + 2 * p]) = facc[k];
}

// ---------------------------------------------------------------------------
// K3: in-place row softmax. 256 blocks x 1024 threads (4 waves/SIMD).
// ---------------------------------------------------------------------------
__global__ __launch_bounds__(1024) void k3_softmax(float* __restrict__ out)
{
    __shared__ float redm[16];
    __shared__ float reds[16];

    const int row = blockIdx.x;
    float* p = out + (size_t)row * LL;
    const int tid = threadIdx.x;

    float4 x = reinterpret_cast<const float4*>(p)[tid];

    float m = fmaxf(fmaxf(x.x, x.y), fmaxf(x.z, x.w));
    #pragma unroll
    for (int off = 32; off > 0; off >>= 1)
        m = fmaxf(m, __shfl_xor(m, off, 64));
    const int lane = tid & 63, wv = tid >> 6;
    if (lane == 0) redm[wv] = m;
    __syncthreads();
    if (tid < 16) {
        float mm = redm[tid];
        #pragma unroll
        for (int off = 8; off > 0; off >>= 1)
            mm = fmaxf(mm, __shfl_xor(mm, off, 64));
        redm[tid] = mm;
    }
    __syncthreads();
    m = redm[0];

    x.x = expf(x.x - m); x.y = expf(x.y - m);
    x.z = expf(x.z - m); x.w = expf(x.w - m);
    float s = (x.x + x.y) + (x.z + x.w);
    #pragma unroll
    for (int off = 32; off > 0; off >>= 1)
        s += __shfl_xor(s, off, 64);
    if (lane == 0) reds[wv] = s;
    __syncthreads();
    if (tid < 16) {
        float ss = reds[tid];
        #pragma unroll
        for (int off = 8; off > 0; off >>= 1)
            ss += __shfl_xor(ss, off, 64);
        reds[tid] = ss;
    }
    __syncthreads();
    s = reds[0];

    const float inv = 1.0f / s;
    x.x *= inv; x.y *= inv; x.z *= inv; x.w *= inv;
    reinterpret_cast<float4*>(p)[tid] = x;
}

// ---------------------------------------------------------------------------
extern "C" void kernel_launch(void* const* d_in, const int* in_sizes, int n_in,
                              void* d_out, int out_size, void* d_ws, size_t ws_size,
                              hipStream_t stream)
{
    const float* inA = (const float*)d_in[0];
    const float* inB = (const float*)d_in[1];
    const float* W1  = (const float*)d_in[2];
    const float* b1  = (const float*)d_in[3];
    const float* w2  = (const float*)d_in[4];
    float* out = (float*)d_out;

    uint32_t* u_dup  = (uint32_t*)d_ws;                            // 128 KiB
    uint32_t* w2_dup = (uint32_t*)((char*)d_ws + 128 * 1024);      // 512 B
    __half*   vT     = (__half*)((char*)d_ws + 128 * 1024 + 512);  // 2 MiB

    hipLaunchKernelGGL(k1_gemm, dim3(528), dim3(256), 0, stream,
                       inA, inB, W1, b1, w2, u_dup, w2_dup, vT);
    hipLaunchKernelGGL(k2_score, dim3(512), dim3(256), 0, stream,
                       u_dup, w2_dup, vT, out);
    hipLaunchKernelGGL(k3_softmax, dim3(BB * KK), dim3(1024), 0, stream, out);
}